// Round 7
// baseline (475.188 us; speedup 1.0000x reference)
//
#include <hip/hip_runtime.h>

// ---------------------------------------------------------------------------
// DeformableTransformer encoder layer, MI355X (gfx950).
// R8 (resubmit; GPUAcquisitionTimeout — never measured):
// deform_sample (32-lane layout kept):
//   - quad-dedup: lane q owns point q of each level; weights/addrs/exp
//     computed once per quad, broadcast via __shfl(width=4)
//   - explicit 2-deep pipeline: prefetch point p+1 (shfl+4 loads) before
//     consuming point p (double-buffered regs, static-indexed post-unroll)
//   - batch->XCD affinity: blockIdx%8 = XCD (m09); XCD k gathers only from
//     batch k/2 (6.7MB slice vs 27MB) -> less L2 thrash, lower FETCH
// R7: 95us, VALU 68%, HBM 26%, FETCH 169MB. Carried: gemm128 dbuf GLDS (R4).
// ---------------------------------------------------------------------------

#define BLTOK 52500   // B*L tokens
#define MP    52608   // BLTOK padded to multiple of 128
#define LSP   13125   // L (spatial length per batch)

using short8  = __attribute__((ext_vector_type(8))) short;
using ushort8v= __attribute__((ext_vector_type(8))) unsigned short;
using f32x4   = __attribute__((ext_vector_type(4))) float;
using fl2     = __attribute__((ext_vector_type(2))) float;

__device__ __forceinline__ ushort f2b(float f) {
  union { float f; unsigned u; } x; x.f = f;
  unsigned r = (x.u + 0x7fffu + ((x.u >> 16) & 1u)) >> 16;
  return (ushort)r;
}
__device__ __forceinline__ float b2f(ushort h) {
  union { unsigned u; float f; } x; x.u = ((unsigned)h) << 16;
  return x.f;
}
__device__ __forceinline__ float blo(uint u) {   // low bf16 of packed uint
  union { unsigned u; float f; } x; x.u = u << 16;
  return x.f;
}
__device__ __forceinline__ float bhi(uint u) {   // high bf16 of packed uint
  union { unsigned u; float f; } x; x.u = u & 0xffff0000u;
  return x.f;
}

#define GLDS16(gp, lp) __builtin_amdgcn_global_load_lds( \
    (const __attribute__((address_space(1))) void*)(gp), \
    (__attribute__((address_space(3))) void*)(lp), 16, 0, 0)

// ---------------- weight prep: transpose to N x K, convert bf16 -------------
__global__ __launch_bounds__(256) void prep_weights(
    const float* __restrict__ Wv, const float* __restrict__ Woff,
    const float* __restrict__ Wattn, const float* __restrict__ Wout,
    const float* __restrict__ Wff1, const float* __restrict__ Wff2,
    const float* __restrict__ boff, const float* __restrict__ battn,
    ushort* __restrict__ wv_t, ushort* __restrict__ wcat_t,
    ushort* __restrict__ wout_t, ushort* __restrict__ wff1_t,
    ushort* __restrict__ wff2_t, float* __restrict__ bcat)
{
  int i = blockIdx.x * 256 + threadIdx.x;
  if (i < 65536) {
    int n = i >> 8, k = i & 255;
    wv_t[i] = f2b(Wv[k * 256 + n]);
    return;
  }
  int j = i - 65536;
  if (j < 98304) {                       // 384 rows (320.. zero)
    int n = j >> 8, k = j & 255;
    float v = (n < 192) ? Woff[k * 192 + n]
            : (n < 288) ? Wattn[k * 96 + (n - 192)] : 0.f;
    wcat_t[j] = f2b(v);
    return;
  }
  j -= 98304;
  if (j < 65536) {
    int n = j >> 8, k = j & 255;
    wout_t[j] = f2b(Wout[k * 256 + n]);
    return;
  }
  j -= 65536;
  if (j < 262144) {
    int n = j >> 8, k = j & 255;
    wff1_t[j] = f2b(Wff1[k * 1024 + n]);
    return;
  }
  j -= 262144;
  if (j < 262144) {
    int n = j >> 10, k = j & 1023;
    wff2_t[j] = f2b(Wff2[k * 256 + n]);
    return;
  }
  j -= 262144;
  if (j < 384) bcat[j] = (j < 192) ? boff[j] : (j < 288) ? battn[j - 192] : 0.f;
}

// ---------------- activation prep: bf16 src and q=src+pos, zero pad rows ----
__global__ __launch_bounds__(256) void prep_act(
    const float* __restrict__ src, const float* __restrict__ pos,
    ushort* __restrict__ src_bf, ushort* __restrict__ q_bf)
{
  const size_t e = ((size_t)blockIdx.x * 256 + threadIdx.x) * 4;
  if (e >= (size_t)MP * 256) return;
  ushort4 sb, qb;
  if (e < (size_t)BLTOK * 256) {
    const float4 s = *(const float4*)(src + e);
    const float4 p = *(const float4*)(pos + e);
    sb.x = f2b(s.x); sb.y = f2b(s.y); sb.z = f2b(s.z); sb.w = f2b(s.w);
    qb.x = f2b(s.x + p.x); qb.y = f2b(s.y + p.y);
    qb.z = f2b(s.z + p.z); qb.w = f2b(s.w + p.w);
  } else {
    sb.x = sb.y = sb.z = sb.w = 0;
    qb.x = qb.y = qb.z = qb.w = 0;
  }
  *(ushort4*)(src_bf + e) = sb;
  *(ushort4*)(q_bf + e) = qb;
}

// ---------------- GEMM 128x128, dbuf GLDS staging, coalesced epilogue -------
// grid = (Ntiles, Mtiles): consecutive blocks share the A m-tile (L2 reuse).
// EPI: 0 = bias; 1 = + addf(f32); 2 = relu; 3 = + addb(bf16)
template <int EPI>
__global__ __launch_bounds__(256) void gemm128(
    const ushort* __restrict__ A, const ushort* __restrict__ Bt,
    const float* __restrict__ bias, const float* __restrict__ addf,
    const ushort* __restrict__ addb, ushort* __restrict__ C,
    int Mact, int Nact, int Nstr, int K)
{
  __shared__ __align__(16) ushort sm[16384];     // 32 KB
  ushort* As = sm;                               // [2][4096]
  ushort* Bs = sm + 8192;                        // [2][4096]
  float*  epf = (float*)sm;                      // epilogue: 64 x 128 f32
  const int tid = threadIdx.x;
  const int wave = tid >> 6, lane = tid & 63;
  const int n0 = blockIdx.x * 128, m0 = blockIdx.y * 128;
  const int srow = lane >> 2, skc = (lane & 3) * 8;
  const ushort* Ag = A + (size_t)(m0 + wave * 32 + srow) * K + skc;
  const ushort* Bg = Bt + (size_t)(n0 + wave * 32 + srow) * K + skc;
  const int quad = lane >> 4, l16 = lane & 15;
  const int wm = (wave & 1) * 64, wn = (wave >> 1) * 64;
  f32x4 acc[4][4] = {};

#define STAGE(buf, kk) { \
    ushort* la = As + (buf) * 4096 + wave * 1024; \
    ushort* lb = Bs + (buf) * 4096 + wave * 1024; \
    GLDS16(Ag + (kk), la); \
    GLDS16(Ag + (kk) + 16 * K, la + 512); \
    GLDS16(Bg + (kk), lb); \
    GLDS16(Bg + (kk) + 16 * K, lb + 512); }

  STAGE(0, 0);
  int cur = 0;
  for (int k0 = 0; k0 < K; k0 += 32) {
    __syncthreads();                      // drains staging of `cur`
    if (k0 + 32 < K) STAGE(cur ^ 1, k0 + 32);   // prefetch overlaps compute
    const ushort* Ab = As + cur * 4096;
    const ushort* Bb = Bs + cur * 4096;
    short8 af[4], bf[4];
#pragma unroll
    for (int i = 0; i < 4; i++)
      af[i] = *(const short8*)(&Ab[(wm + i * 16 + l16) * 32 + quad * 8]);
#pragma unroll
    for (int j = 0; j < 4; j++)
      bf[j] = *(const short8*)(&Bb[(wn + j * 16 + l16) * 32 + quad * 8]);
#pragma unroll
    for (int i = 0; i < 4; i++)
#pragma unroll
      for (int j = 0; j < 4; j++)
        acc[i][j] = __builtin_amdgcn_mfma_f32_16x16x32_bf16(af[i], bf[j],
                                                            acc[i][j], 0, 0, 0);
    cur ^= 1;
  }
#undef STAGE

  // coalesced epilogue: two 64-row rounds through f32 LDS
  for (int half = 0; half < 2; half++) {
    __syncthreads();
    if ((wave & 1) == half) {
      // C/D: col = l16, row = quad*4 + r  [m89/m91]
#pragma unroll
      for (int i = 0; i < 4; i++)
#pragma unroll
        for (int j = 0; j < 4; j++)
#pragma unroll
          for (int r = 0; r < 4; r++)
            epf[(i * 16 + quad * 4 + r) * 128 + wn + j * 16 + l16] = acc[i][j][r];
    }
    __syncthreads();
    const int gm0 = m0 + half * 64;
#pragma unroll
    for (int g = 0; g < 4; g++) {
      const int lrow = g * 16 + (tid >> 4);
      const int col0 = (tid & 15) * 8;
      const int grow = gm0 + lrow;
      const int gcol = n0 + col0;
      if (grow < Mact && gcol < Nact) {
        float v[8];
#pragma unroll
        for (int c = 0; c < 8; c++) v[c] = epf[lrow * 128 + col0 + c] + bias[gcol + c];
        const size_t idx = (size_t)grow * Nstr + gcol;
        if (EPI == 1) {
          const float4 a0 = *(const float4*)(addf + idx);
          const float4 a1 = *(const float4*)(addf + idx + 4);
          v[0] += a0.x; v[1] += a0.y; v[2] += a0.z; v[3] += a0.w;
          v[4] += a1.x; v[5] += a1.y; v[6] += a1.z; v[7] += a1.w;
        }
        if (EPI == 2) {
#pragma unroll
          for (int c = 0; c < 8; c++) v[c] = fmaxf(v[c], 0.f);
        }
        if (EPI == 3) {
          const ushort8v ab = *(const ushort8v*)(addb + idx);
#pragma unroll
          for (int c = 0; c < 8; c++) v[c] += b2f(ab[c]);
        }
        ushort8v o;
#pragma unroll
        for (int c = 0; c < 8; c++) o[c] = f2b(v[c]);
        *(ushort8v*)(C + idx) = o;
      }
    }
  }
}

// ---------------- MS-deform-attn bilinear sampling core ---------------------
// 32 lanes/token. Lane q of each head-quad OWNS point q of each level:
// computes softmax-exp + bilinear weights + corner addresses once; broadcast
// to the quad via __shfl(width=4). 2-deep prefetch pipeline on corner loads.
__global__ __launch_bounds__(256) void deform_sample(
    const ushort* __restrict__ value, const ushort* __restrict__ oa_all,
    const float* __restrict__ refp, ushort* __restrict__ outb)
{
  const int tid = threadIdx.x;
  // batch->XCD affinity: XCD = blockIdx%8 (m09 round-robin); XCD k serves
  // batch k/2, half k&1. Each XCD's gathers hit one 6.7MB value slice.
  const int xcd  = blockIdx.x & 7;
  const int slot = blockIdx.x >> 3;
  const int batch = xcd >> 1, halfb = xcd & 1;
  const int tok = batch * LSP + halfb * 6564 + slot * 8 + (tid >> 5);
  const int tokEnd = batch * LSP + (halfb ? LSP : 6564);
  if (tok >= tokEnd) return;
  const int l = tid & 31;
  const int h = l >> 2;
  const int q = l & 3;
  const ushort* oa = oa_all + (uint)tok * 320u;
  const float* rp = refp + (uint)tok * 6u;
  const uint base = (uint)batch * (LSP * 256u) + (uint)(l * 8);

  const int Wl[3] = {100, 50, 25};
  const int Stl[3] = {0, 10000, 12500};

  // ---- quad-parallel softmax over 12 logits (lane q: logits q, q+4, q+8) --
  const ushort* lgp = oa + 192 + h * 12 + q;
  float e0 = b2f(lgp[0]), e1 = b2f(lgp[4]), e2 = b2f(lgp[8]);
  float m3 = fmaxf(fmaxf(e0, e1), e2);
  m3 = fmaxf(m3, __shfl_xor(m3, 1, 4));
  m3 = fmaxf(m3, __shfl_xor(m3, 2, 4));
  e0 = __expf(e0 - m3); e1 = __expf(e1 - m3); e2 = __expf(e2 - m3);
  float s3 = e0 + e1 + e2;
  s3 += __shfl_xor(s3, 1, 4);
  s3 += __shfl_xor(s3, 2, 4);
  const float inv = __builtin_amdgcn_rcpf(s3);
  const float awn[3] = {e0 * inv, e1 * inv, e2 * inv};

  // ---- owned-point math: point q of each level ----------------------------
  float ow[3][4];   // w00,w10,w01,w11 (attn-folded, validity-masked)
  uint  orr[3][4];  // corner row offsets (elements)
#pragma unroll
  for (int lid = 0; lid < 3; lid++) {
    const int W = Wl[lid], st = Stl[lid];   // square levels: H == W
    const float Wf = (float)W;
    const uint o = *(const uint*)(oa + h * 24 + lid * 8 + q * 2);
    const float aw = awn[lid];
    const float x = rp[lid * 2] * Wf - 0.5f + blo(o);   // == (rx+ox/W)*W-0.5
    const float y = rp[lid * 2 + 1] * Wf - 0.5f + bhi(o);
    const float x0f = floorf(x), y0f = floorf(y);
    const float wx1 = x - x0f, wy1 = y - y0f;
    const float wx0 = 1.f - wx1, wy0 = 1.f - wy1;
    const int ix0 = (int)x0f, iy0 = (int)y0f;
    const bool x0v = (ix0 >= 0) & (ix0 < W);
    const bool x1v = (ix0 + 1 >= 0) & (ix0 + 1 < W);
    const bool y0v = (iy0 >= 0) & (iy0 < W);
    const bool y1v = (iy0 + 1 >= 0) & (iy0 + 1 < W);
    const float ay0 = aw * wy0, ay1 = aw * wy1;
    ow[lid][0] = (x0v & y0v) ? ay0 * wx0 : 0.f;
    ow[lid][1] = (x1v & y0v) ? ay0 * wx1 : 0.f;
    ow[lid][2] = (x0v & y1v) ? ay1 * wx0 : 0.f;
    ow[lid][3] = (x1v & y1v) ? ay1 * wx1 : 0.f;
    const int ix0c = min(max(ix0, 0), W - 1);
    const int ix1c = min(max(ix0 + 1, 0), W - 1);
    const int iy0c = min(max(iy0, 0), W - 1);
    const int iy1c = min(max(iy0 + 1, 0), W - 1);
    orr[lid][0] = (uint)(st + iy0c * W + ix0c) * 256u;
    orr[lid][1] = (uint)(st + iy0c * W + ix1c) * 256u;
    orr[lid][2] = (uint)(st + iy1c * W + ix0c) * 256u;
    orr[lid][3] = (uint)(st + iy1c * W + ix1c) * 256u;
  }

  // ---- main loop: 12 points, 2-deep prefetch (shfl broadcast + 4 loads) ---
  fl2 acc2[4] = {};
  float bww[2][4];
  uint4 cq[2][4];

#define PRE(p, s) { \
    const int lid_ = (p) >> 2, own_ = (p) & 3; \
    bww[s][0] = __shfl(ow[lid_][0], own_, 4); \
    bww[s][1] = __shfl(ow[lid_][1], own_, 4); \
    bww[s][2] = __shfl(ow[lid_][2], own_, 4); \
    bww[s][3] = __shfl(ow[lid_][3], own_, 4); \
    const uint r0_ = (uint)__shfl((int)orr[lid_][0], own_, 4); \
    const uint r1_ = (uint)__shfl((int)orr[lid_][1], own_, 4); \
    const uint r2_ = (uint)__shfl((int)orr[lid_][2], own_, 4); \
    const uint r3_ = (uint)__shfl((int)orr[lid_][3], own_, 4); \
    cq[s][0] = *(const uint4*)(value + base + r0_); \
    cq[s][1] = *(const uint4*)(value + base + r1_); \
    cq[s][2] = *(const uint4*)(value + base + r2_); \
    cq[s][3] = *(const uint4*)(value + base + r3_); }

#define CONS(s) { \
    _Pragma("unroll") \
    for (int c_ = 0; c_ < 4; c_++) { \
      const fl2 wv_ = {bww[s][c_], bww[s][c_]}; \
      const uint* u_ = (const uint*)&cq[s][c_]; \
      _Pragma("unroll") \
      for (int pp_ = 0; pp_ < 4; pp_++) { \
        const fl2 vv_ = {blo(u_[pp_]), bhi(u_[pp_])}; \
        acc2[pp_] += wv_ * vv_; \
      } \
    } }

  PRE(0, 0);
#pragma unroll
  for (int p = 0; p < 12; p++) {
    if (p < 11) PRE(p + 1, (p + 1) & 1);
    CONS(p & 1);
  }
#undef PRE
#undef CONS

  ushort4 o0, o1;
  o0.x = f2b(acc2[0].x); o0.y = f2b(acc2[0].y);
  o0.z = f2b(acc2[1].x); o0.w = f2b(acc2[1].y);
  o1.x = f2b(acc2[2].x); o1.y = f2b(acc2[2].y);
  o1.z = f2b(acc2[3].x); o1.w = f2b(acc2[3].y);
  ushort* op = outb + (uint)tok * 256u + (uint)(l * 8);
  *(ushort4*)op = o0;
  *(ushort4*)(op + 4) = o1;
}

// ---------------- LayerNorm over 256 (wave per row, 4 rows/block) -----------
template <int OUTF>
__global__ __launch_bounds__(256) void ln256(
    const ushort* __restrict__ in, const float* __restrict__ gg,
    const float* __restrict__ bb, ushort* __restrict__ outb,
    float* __restrict__ outf, int rows)
{
  const int wave = threadIdx.x >> 6, lane = threadIdx.x & 63;
  const int r = blockIdx.x * 4 + wave;
  if (r >= rows) return;
  const ushort* rowp = in + (size_t)r * 256;
  const ushort4 u = *(const ushort4*)(rowp + lane * 4);
  float v[4] = {b2f(u.x), b2f(u.y), b2f(u.z), b2f(u.w)};
  float s = v[0] + v[1] + v[2] + v[3];
  float s2 = v[0] * v[0] + v[1] * v[1] + v[2] * v[2] + v[3] * v[3];
#pragma unroll
  for (int o = 32; o > 0; o >>= 1) {
    s += __shfl_xor(s, o);
    s2 += __shfl_xor(s2, o);
  }
  const float mean = s * (1.f / 256.f);
  const float var = s2 * (1.f / 256.f) - mean * mean;
  const float rstd = rsqrtf(var + 1e-5f);
#pragma unroll
  for (int j = 0; j < 4; j++) {
    const int col = lane * 4 + j;
    const float o = (v[j] - mean) * rstd * gg[col] + bb[col];
    if (OUTF) outf[(size_t)r * 256 + col] = o;
    else outb[(size_t)r * 256 + col] = f2b(o);
  }
}

// ---------------------------------------------------------------------------
extern "C" void kernel_launch(void* const* d_in, const int* in_sizes, int n_in,
                              void* d_out, int out_size, void* d_ws, size_t ws_size,
                              hipStream_t stream)
{
  const float* src   = (const float*)d_in[0];
  const float* pos   = (const float*)d_in[1];
  const float* refp  = (const float*)d_in[2];
  const float* Wv    = (const float*)d_in[3];
  const float* bv    = (const float*)d_in[4];
  const float* Woff  = (const float*)d_in[5];
  const float* boff  = (const float*)d_in[6];
  const float* Wattn = (const float*)d_in[7];
  const float* battn = (const float*)d_in[8];
  const float* Wout  = (const float*)d_in[9];
  const float* bout  = (const float*)d_in[10];
  const float* g1    = (const float*)d_in[11];
  const float* b1    = (const float*)d_in[12];
  const float* Wff1  = (const float*)d_in[13];
  const float* bff1  = (const float*)d_in[14];
  const float* Wff2  = (const float*)d_in[15];
  const float* bff2  = (const float*)d_in[16];
  const float* g2    = (const float*)d_in[17];
  const float* b2    = (const float*)d_in[18];
  float* out = (float*)d_out;
  char* ws = (char*)d_ws;

  // workspace (bytes). wv_t / wout_t overlaid on A5 tail (dead before G4
  // writes h there); attn_out uses A5's head (dead until G4).
  ushort* wcat_t = (ushort*)(ws + 0);            //   196608 (384 x 256)
  ushort* wff1_t = (ushort*)(ws + 196608);       //   524288
  ushort* wff2_t = (ushort*)(ws + 720896);       //   524288
  float*  bcat   = (float*)(ws + 1245184);       //     1536
  ushort* A1 = (ushort*)(ws + 1246720);          // src_bf (lives to G3)
  ushort* A2 = (ushort*)(ws + 28182016);         // q_bf -> x_bf
  ushort* A3 = (ushort*)(ws + 55117312);         // value -> y_bf
  ushort* A4 = (ushort*)(ws + 81997312);         // offattn(320) -> xpre(256)
  ushort* A5 = (ushort*)(ws + 115597312);        // attn_out (head) -> h (MPx1024)
  ushort* wout_t = (ushort*)(ws + 223076352);    //   131072 (A5 tail)
  ushort* wv_t   = (ushort*)(ws + 223207424);    //   131072 (A5 tail)
  // end: 223338496

  prep_weights<<<2946, 256, 0, stream>>>(Wv, Woff, Wattn, Wout, Wff1, Wff2,
                                         boff, battn,
                                         wv_t, wcat_t, wout_t, wff1_t, wff2_t, bcat);
  prep_act<<<MP / 4, 256, 0, stream>>>(src, pos, A1, A2);
  // G1: value = src @ Wv + bv
  gemm128<0><<<dim3(2, MP / 128), 256, 0, stream>>>(A1, wv_t, bv, nullptr, nullptr,
                                                    A3, BLTOK, 256, 256, 256);
  // G2: offattn = q @ Wcat + bcat  (N=320, tiles to 384)
  gemm128<0><<<dim3(3, MP / 128), 256, 0, stream>>>(A2, wcat_t, bcat, nullptr, nullptr,
                                                    A4, BLTOK, 320, 320, 256);
  // attn_out -> A5 head  (quad-dedup + batch-XCD affinity; grid 8*821)
  deform_sample<<<8 * 821, 256, 0, stream>>>(A3, A4, refp, A5);
  // G3: xpre = src_bf + attn_out @ Wout + bout  (bf16 residual from A1)
  gemm128<3><<<dim3(2, MP / 128), 256, 0, stream>>>(A5, wout_t, bout, nullptr, A1,
                                                    A4, BLTOK, 256, 256, 256);
  ln256<0><<<BLTOK / 4, 256, 0, stream>>>(A4, g1, b1, A2, nullptr, BLTOK);
  // G4: h = relu(x @ Wff1 + bff1) — store pad rows too (A2 pads are zero)
  gemm128<2><<<dim3(8, MP / 128), 256, 0, stream>>>(A2, wff1_t, bff1, nullptr, nullptr,
                                                    A5, MP, 1024, 1024, 256);
  // G5: y = x + h @ Wff2 + bff2
  gemm128<3><<<dim3(2, MP / 128), 256, 0, stream>>>(A5, wff2_t, bff2, nullptr, A2,
                                                    A3, BLTOK, 256, 256, 1024);
  ln256<1><<<BLTOK / 4, 256, 0, stream>>>(A3, g2, b2, nullptr, out, BLTOK);
}

// Round 9
// 469.329 us; speedup vs baseline: 1.0125x; 1.0125x over previous
//
#include <hip/hip_runtime.h>

// ---------------------------------------------------------------------------
// DeformableTransformer encoder layer, MI355X (gfx950).
// R9 (resubmit; GPUAcquisitionTimeout — never measured):
// deform_sample MLP fix. R8's 2-deep prefetch was COLLAPSED by the
// compiler (VGPR=32 proves loads were sunk to their uses -> 4 in flight,
// latency-bound: VALU 42%, HBM 24%, occ 72%, dur flat at 95us).
// New: per-level batch of ALL 16 corner loads into regs, pinned above the
// consume phase with sched_barrier(0) (3 total). 16 loads in flight/wave.
// Carried: quad-dedup softmax/weights (R8), batch->XCD affinity (R8),
// 32-lane/token layout (R5/R7), gemm128 dbuf GLDS (R4).
// ---------------------------------------------------------------------------

#define BLTOK 52500   // B*L tokens
#define MP    52608   // BLTOK padded to multiple of 128
#define LSP   13125   // L (spatial length per batch)

using short8  = __attribute__((ext_vector_type(8))) short;
using ushort8v= __attribute__((ext_vector_type(8))) unsigned short;
using f32x4   = __attribute__((ext_vector_type(4))) float;
using fl2     = __attribute__((ext_vector_type(2))) float;

__device__ __forceinline__ ushort f2b(float f) {
  union { float f; unsigned u; } x; x.f = f;
  unsigned r = (x.u + 0x7fffu + ((x.u >> 16) & 1u)) >> 16;
  return (ushort)r;
}
__device__ __forceinline__ float b2f(ushort h) {
  union { unsigned u; float f; } x; x.u = ((unsigned)h) << 16;
  return x.f;
}
__device__ __forceinline__ float blo(uint u) {   // low bf16 of packed uint
  union { unsigned u; float f; } x; x.u = u << 16;
  return x.f;
}
__device__ __forceinline__ float bhi(uint u) {   // high bf16 of packed uint
  union { unsigned u; float f; } x; x.u = u & 0xffff0000u;
  return x.f;
}

#define GLDS16(gp, lp) __builtin_amdgcn_global_load_lds( \
    (const __attribute__((address_space(1))) void*)(gp), \
    (__attribute__((address_space(3))) void*)(lp), 16, 0, 0)

// ---------------- weight prep: transpose to N x K, convert bf16 -------------
__global__ __launch_bounds__(256) void prep_weights(
    const float* __restrict__ Wv, const float* __restrict__ Woff,
    const float* __restrict__ Wattn, const float* __restrict__ Wout,
    const float* __restrict__ Wff1, const float* __restrict__ Wff2,
    const float* __restrict__ boff, const float* __restrict__ battn,
    ushort* __restrict__ wv_t, ushort* __restrict__ wcat_t,
    ushort* __restrict__ wout_t, ushort* __restrict__ wff1_t,
    ushort* __restrict__ wff2_t, float* __restrict__ bcat)
{
  int i = blockIdx.x * 256 + threadIdx.x;
  if (i < 65536) {
    int n = i >> 8, k = i & 255;
    wv_t[i] = f2b(Wv[k * 256 + n]);
    return;
  }
  int j = i - 65536;
  if (j < 98304) {                       // 384 rows (320.. zero)
    int n = j >> 8, k = j & 255;
    float v = (n < 192) ? Woff[k * 192 + n]
            : (n < 288) ? Wattn[k * 96 + (n - 192)] : 0.f;
    wcat_t[j] = f2b(v);
    return;
  }
  j -= 98304;
  if (j < 65536) {
    int n = j >> 8, k = j & 255;
    wout_t[j] = f2b(Wout[k * 256 + n]);
    return;
  }
  j -= 65536;
  if (j < 262144) {
    int n = j >> 8, k = j & 255;
    wff1_t[j] = f2b(Wff1[k * 1024 + n]);
    return;
  }
  j -= 262144;
  if (j < 262144) {
    int n = j >> 10, k = j & 1023;
    wff2_t[j] = f2b(Wff2[k * 256 + n]);
    return;
  }
  j -= 262144;
  if (j < 384) bcat[j] = (j < 192) ? boff[j] : (j < 288) ? battn[j - 192] : 0.f;
}

// ---------------- activation prep: bf16 src and q=src+pos, zero pad rows ----
__global__ __launch_bounds__(256) void prep_act(
    const float* __restrict__ src, const float* __restrict__ pos,
    ushort* __restrict__ src_bf, ushort* __restrict__ q_bf)
{
  const size_t e = ((size_t)blockIdx.x * 256 + threadIdx.x) * 4;
  if (e >= (size_t)MP * 256) return;
  ushort4 sb, qb;
  if (e < (size_t)BLTOK * 256) {
    const float4 s = *(const float4*)(src + e);
    const float4 p = *(const float4*)(pos + e);
    sb.x = f2b(s.x); sb.y = f2b(s.y); sb.z = f2b(s.z); sb.w = f2b(s.w);
    qb.x = f2b(s.x + p.x); qb.y = f2b(s.y + p.y);
    qb.z = f2b(s.z + p.z); qb.w = f2b(s.w + p.w);
  } else {
    sb.x = sb.y = sb.z = sb.w = 0;
    qb.x = qb.y = qb.z = qb.w = 0;
  }
  *(ushort4*)(src_bf + e) = sb;
  *(ushort4*)(q_bf + e) = qb;
}

// ---------------- GEMM 128x128, dbuf GLDS staging, coalesced epilogue -------
// grid = (Ntiles, Mtiles): consecutive blocks share the A m-tile (L2 reuse).
// EPI: 0 = bias; 1 = + addf(f32); 2 = relu; 3 = + addb(bf16)
template <int EPI>
__global__ __launch_bounds__(256) void gemm128(
    const ushort* __restrict__ A, const ushort* __restrict__ Bt,
    const float* __restrict__ bias, const float* __restrict__ addf,
    const ushort* __restrict__ addb, ushort* __restrict__ C,
    int Mact, int Nact, int Nstr, int K)
{
  __shared__ __align__(16) ushort sm[16384];     // 32 KB
  ushort* As = sm;                               // [2][4096]
  ushort* Bs = sm + 8192;                        // [2][4096]
  float*  epf = (float*)sm;                      // epilogue: 64 x 128 f32
  const int tid = threadIdx.x;
  const int wave = tid >> 6, lane = tid & 63;
  const int n0 = blockIdx.x * 128, m0 = blockIdx.y * 128;
  const int srow = lane >> 2, skc = (lane & 3) * 8;
  const ushort* Ag = A + (size_t)(m0 + wave * 32 + srow) * K + skc;
  const ushort* Bg = Bt + (size_t)(n0 + wave * 32 + srow) * K + skc;
  const int quad = lane >> 4, l16 = lane & 15;
  const int wm = (wave & 1) * 64, wn = (wave >> 1) * 64;
  f32x4 acc[4][4] = {};

#define STAGE(buf, kk) { \
    ushort* la = As + (buf) * 4096 + wave * 1024; \
    ushort* lb = Bs + (buf) * 4096 + wave * 1024; \
    GLDS16(Ag + (kk), la); \
    GLDS16(Ag + (kk) + 16 * K, la + 512); \
    GLDS16(Bg + (kk), lb); \
    GLDS16(Bg + (kk) + 16 * K, lb + 512); }

  STAGE(0, 0);
  int cur = 0;
  for (int k0 = 0; k0 < K; k0 += 32) {
    __syncthreads();                      // drains staging of `cur`
    if (k0 + 32 < K) STAGE(cur ^ 1, k0 + 32);   // prefetch overlaps compute
    const ushort* Ab = As + cur * 4096;
    const ushort* Bb = Bs + cur * 4096;
    short8 af[4], bf[4];
#pragma unroll
    for (int i = 0; i < 4; i++)
      af[i] = *(const short8*)(&Ab[(wm + i * 16 + l16) * 32 + quad * 8]);
#pragma unroll
    for (int j = 0; j < 4; j++)
      bf[j] = *(const short8*)(&Bb[(wn + j * 16 + l16) * 32 + quad * 8]);
#pragma unroll
    for (int i = 0; i < 4; i++)
#pragma unroll
      for (int j = 0; j < 4; j++)
        acc[i][j] = __builtin_amdgcn_mfma_f32_16x16x32_bf16(af[i], bf[j],
                                                            acc[i][j], 0, 0, 0);
    cur ^= 1;
  }
#undef STAGE

  // coalesced epilogue: two 64-row rounds through f32 LDS
  for (int half = 0; half < 2; half++) {
    __syncthreads();
    if ((wave & 1) == half) {
      // C/D: col = l16, row = quad*4 + r  [m89/m91]
#pragma unroll
      for (int i = 0; i < 4; i++)
#pragma unroll
        for (int j = 0; j < 4; j++)
#pragma unroll
          for (int r = 0; r < 4; r++)
            epf[(i * 16 + quad * 4 + r) * 128 + wn + j * 16 + l16] = acc[i][j][r];
    }
    __syncthreads();
    const int gm0 = m0 + half * 64;
#pragma unroll
    for (int g = 0; g < 4; g++) {
      const int lrow = g * 16 + (tid >> 4);
      const int col0 = (tid & 15) * 8;
      const int grow = gm0 + lrow;
      const int gcol = n0 + col0;
      if (grow < Mact && gcol < Nact) {
        float v[8];
#pragma unroll
        for (int c = 0; c < 8; c++) v[c] = epf[lrow * 128 + col0 + c] + bias[gcol + c];
        const size_t idx = (size_t)grow * Nstr + gcol;
        if (EPI == 1) {
          const float4 a0 = *(const float4*)(addf + idx);
          const float4 a1 = *(const float4*)(addf + idx + 4);
          v[0] += a0.x; v[1] += a0.y; v[2] += a0.z; v[3] += a0.w;
          v[4] += a1.x; v[5] += a1.y; v[6] += a1.z; v[7] += a1.w;
        }
        if (EPI == 2) {
#pragma unroll
          for (int c = 0; c < 8; c++) v[c] = fmaxf(v[c], 0.f);
        }
        if (EPI == 3) {
          const ushort8v ab = *(const ushort8v*)(addb + idx);
#pragma unroll
          for (int c = 0; c < 8; c++) v[c] += b2f(ab[c]);
        }
        ushort8v o;
#pragma unroll
        for (int c = 0; c < 8; c++) o[c] = f2b(v[c]);
        *(ushort8v*)(C + idx) = o;
      }
    }
  }
}

// ---------------- MS-deform-attn bilinear sampling core ---------------------
// 32 lanes/token. Lane q of each head-quad owns point q of each level
// (weights/addrs/exp computed once, broadcast via DPP __shfl width=4).
// Per level: issue ALL 16 corner loads into regs, sched_barrier(0) pins them
// above the consume phase -> 16 loads in flight per wave (MLP fix).
__global__ __launch_bounds__(256) void deform_sample(
    const ushort* __restrict__ value, const ushort* __restrict__ oa_all,
    const float* __restrict__ refp, ushort* __restrict__ outb)
{
  const int tid = threadIdx.x;
  // batch->XCD affinity: XCD = blockIdx%8 (m09 round-robin); XCD k serves
  // batch k/2, half k&1. Each XCD's gathers hit one 6.7MB value slice.
  const int xcd  = blockIdx.x & 7;
  const int slot = blockIdx.x >> 3;
  const int batch = xcd >> 1, halfb = xcd & 1;
  const int tok = batch * LSP + halfb * 6564 + slot * 8 + (tid >> 5);
  const int tokEnd = batch * LSP + (halfb ? LSP : 6564);
  if (tok >= tokEnd) return;
  const int l = tid & 31;
  const int h = l >> 2;
  const int q = l & 3;
  const ushort* oa = oa_all + (uint)tok * 320u;
  const float* rp = refp + (uint)tok * 6u;
  const uint base = (uint)batch * (LSP * 256u) + (uint)(l * 8);

  const int Wl[3] = {100, 50, 25};
  const int Stl[3] = {0, 10000, 12500};

  // ---- quad-parallel softmax over 12 logits (lane q: logits q, q+4, q+8) --
  const ushort* lgp = oa + 192 + h * 12 + q;
  float e0 = b2f(lgp[0]), e1 = b2f(lgp[4]), e2 = b2f(lgp[8]);
  float m3 = fmaxf(fmaxf(e0, e1), e2);
  m3 = fmaxf(m3, __shfl_xor(m3, 1, 4));
  m3 = fmaxf(m3, __shfl_xor(m3, 2, 4));
  e0 = __expf(e0 - m3); e1 = __expf(e1 - m3); e2 = __expf(e2 - m3);
  float s3 = e0 + e1 + e2;
  s3 += __shfl_xor(s3, 1, 4);
  s3 += __shfl_xor(s3, 2, 4);
  const float inv = __builtin_amdgcn_rcpf(s3);
  const float awn[3] = {e0 * inv, e1 * inv, e2 * inv};

  // ---- owned-point math: point q of each level ----------------------------
  float ow[3][4];   // w00,w10,w01,w11 (attn-folded, validity-masked)
  uint  orr[3][4];  // corner row offsets (elements)
#pragma unroll
  for (int lid = 0; lid < 3; lid++) {
    const int W = Wl[lid], st = Stl[lid];   // square levels: H == W
    const float Wf = (float)W;
    const uint o = *(const uint*)(oa + h * 24 + lid * 8 + q * 2);
    const float aw = awn[lid];
    const float x = rp[lid * 2] * Wf - 0.5f + blo(o);   // == (rx+ox/W)*W-0.5
    const float y = rp[lid * 2 + 1] * Wf - 0.5f + bhi(o);
    const float x0f = floorf(x), y0f = floorf(y);
    const float wx1 = x - x0f, wy1 = y - y0f;
    const float wx0 = 1.f - wx1, wy0 = 1.f - wy1;
    const int ix0 = (int)x0f, iy0 = (int)y0f;
    const bool x0v = (ix0 >= 0) & (ix0 < W);
    const bool x1v = (ix0 + 1 >= 0) & (ix0 + 1 < W);
    const bool y0v = (iy0 >= 0) & (iy0 < W);
    const bool y1v = (iy0 + 1 >= 0) & (iy0 + 1 < W);
    const float ay0 = aw * wy0, ay1 = aw * wy1;
    ow[lid][0] = (x0v & y0v) ? ay0 * wx0 : 0.f;
    ow[lid][1] = (x1v & y0v) ? ay0 * wx1 : 0.f;
    ow[lid][2] = (x0v & y1v) ? ay1 * wx0 : 0.f;
    ow[lid][3] = (x1v & y1v) ? ay1 * wx1 : 0.f;
    const int ix0c = min(max(ix0, 0), W - 1);
    const int ix1c = min(max(ix0 + 1, 0), W - 1);
    const int iy0c = min(max(iy0, 0), W - 1);
    const int iy1c = min(max(iy0 + 1, 0), W - 1);
    orr[lid][0] = (uint)(st + iy0c * W + ix0c) * 256u;
    orr[lid][1] = (uint)(st + iy0c * W + ix1c) * 256u;
    orr[lid][2] = (uint)(st + iy1c * W + ix0c) * 256u;
    orr[lid][3] = (uint)(st + iy1c * W + ix1c) * 256u;
  }

  // ---- per level: broadcast 16 (w,addr), issue 16 loads, pin, consume -----
  fl2 acc2[4] = {};
#pragma unroll
  for (int lid = 0; lid < 3; lid++) {
    float bw[4][4];
    uint4 cq[4][4];
#pragma unroll
    for (int pt = 0; pt < 4; pt++) {
#pragma unroll
      for (int c = 0; c < 4; c++) {
        bw[pt][c] = __shfl(ow[lid][c], pt, 4);          // DPP quad_perm
        const uint r = (uint)__shfl((int)orr[lid][c], pt, 4);
        cq[pt][c] = *(const uint4*)(value + base + r);
      }
    }
    __builtin_amdgcn_sched_barrier(0);   // keep the 16 loads ABOVE the math
#pragma unroll
    for (int pt = 0; pt < 4; pt++) {
#pragma unroll
      for (int c = 0; c < 4; c++) {
        const fl2 wv = {bw[pt][c], bw[pt][c]};
        const uint* u = (const uint*)&cq[pt][c];
#pragma unroll
        for (int pp = 0; pp < 4; pp++) {
          const fl2 vv = {blo(u[pp]), bhi(u[pp])};
          acc2[pp] += wv * vv;
        }
      }
    }
  }

  ushort4 o0, o1;
  o0.x = f2b(acc2[0].x); o0.y = f2b(acc2[0].y);
  o0.z = f2b(acc2[1].x); o0.w = f2b(acc2[1].y);
  o1.x = f2b(acc2[2].x); o1.y = f2b(acc2[2].y);
  o1.z = f2b(acc2[3].x); o1.w = f2b(acc2[3].y);
  ushort* op = outb + (uint)tok * 256u + (uint)(l * 8);
  *(ushort4*)op = o0;
  *(ushort4*)(op + 4) = o1;
}

// ---------------- LayerNorm over 256 (wave per row, 4 rows/block) -----------
template <int OUTF>
__global__ __launch_bounds__(256) void ln256(
    const ushort* __restrict__ in, const float* __restrict__ gg,
    const float* __restrict__ bb, ushort* __restrict__ outb,
    float* __restrict__ outf, int rows)
{
  const int wave = threadIdx.x >> 6, lane = threadIdx.x & 63;
  const int r = blockIdx.x * 4 + wave;
  if (r >= rows) return;
  const ushort* rowp = in + (size_t)r * 256;
  const ushort4 u = *(const ushort4*)(rowp + lane * 4);
  float v[4] = {b2f(u.x), b2f(u.y), b2f(u.z), b2f(u.w)};
  float s = v[0] + v[1] + v[2] + v[3];
  float s2 = v[0] * v[0] + v[1] * v[1] + v[2] * v[2] + v[3] * v[3];
#pragma unroll
  for (int o = 32; o > 0; o >>= 1) {
    s += __shfl_xor(s, o);
    s2 += __shfl_xor(s2, o);
  }
  const float mean = s * (1.f / 256.f);
  const float var = s2 * (1.f / 256.f) - mean * mean;
  const float rstd = rsqrtf(var + 1e-5f);
#pragma unroll
  for (int j = 0; j < 4; j++) {
    const int col = lane * 4 + j;
    const float o = (v[j] - mean) * rstd * gg[col] + bb[col];
    if (OUTF) outf[(size_t)r * 256 + col] = o;
    else outb[(size_t)r * 256 + col] = f2b(o);
  }
}

// ---------------------------------------------------------------------------
extern "C" void kernel_launch(void* const* d_in, const int* in_sizes, int n_in,
                              void* d_out, int out_size, void* d_ws, size_t ws_size,
                              hipStream_t stream)
{
  const float* src   = (const float*)d_in[0];
  const float* pos   = (const float*)d_in[1];
  const float* refp  = (const float*)d_in[2];
  const float* Wv    = (const float*)d_in[3];
  const float* bv    = (const float*)d_in[4];
  const float* Woff  = (const float*)d_in[5];
  const float* boff  = (const float*)d_in[6];
  const float* Wattn = (const float*)d_in[7];
  const float* battn = (const float*)d_in[8];
  const float* Wout  = (const float*)d_in[9];
  const float* bout  = (const float*)d_in[10];
  const float* g1    = (const float*)d_in[11];
  const float* b1    = (const float*)d_in[12];
  const float* Wff1  = (const float*)d_in[13];
  const float* bff1  = (const float*)d_in[14];
  const float* Wff2  = (const float*)d_in[15];
  const float* bff2  = (const float*)d_in[16];
  const float* g2    = (const float*)d_in[17];
  const float* b2    = (const float*)d_in[18];
  float* out = (float*)d_out;
  char* ws = (char*)d_ws;

  // workspace (bytes). wv_t / wout_t overlaid on A5 tail (dead before G4
  // writes h there); attn_out uses A5's head (dead until G4).
  ushort* wcat_t = (ushort*)(ws + 0);            //   196608 (384 x 256)
  ushort* wff1_t = (ushort*)(ws + 196608);       //   524288
  ushort* wff2_t = (ushort*)(ws + 720896);       //   524288
  float*  bcat   = (float*)(ws + 1245184);       //     1536
  ushort* A1 = (ushort*)(ws + 1246720);          // src_bf (lives to G3)
  ushort* A2 = (ushort*)(ws + 28182016);         // q_bf -> x_bf
  ushort* A3 = (ushort*)(ws + 55117312);         // value -> y_bf
  ushort* A4 = (ushort*)(ws + 81997312);         // offattn(320) -> xpre(256)
  ushort* A5 = (ushort*)(ws + 115597312);        // attn_out (head) -> h (MPx1024)
  ushort* wout_t = (ushort*)(ws + 223076352);    //   131072 (A5 tail)
  ushort* wv_t   = (ushort*)(ws + 223207424);    //   131072 (A5 tail)
  // end: 223338496

  prep_weights<<<2946, 256, 0, stream>>>(Wv, Woff, Wattn, Wout, Wff1, Wff2,
                                         boff, battn,
                                         wv_t, wcat_t, wout_t, wff1_t, wff2_t, bcat);
  prep_act<<<MP / 4, 256, 0, stream>>>(src, pos, A1, A2);
  // G1: value = src @ Wv + bv
  gemm128<0><<<dim3(2, MP / 128), 256, 0, stream>>>(A1, wv_t, bv, nullptr, nullptr,
                                                    A3, BLTOK, 256, 256, 256);
  // G2: offattn = q @ Wcat + bcat  (N=320, tiles to 384)
  gemm128<0><<<dim3(3, MP / 128), 256, 0, stream>>>(A2, wcat_t, bcat, nullptr, nullptr,
                                                    A4, BLTOK, 320, 320, 256);
  // attn_out -> A5 head  (quad-dedup + level-batch MLP + XCD affinity)
  deform_sample<<<8 * 821, 256, 0, stream>>>(A3, A4, refp, A5);
  // G3: xpre = src_bf + attn_out @ Wout + bout  (bf16 residual from A1)
  gemm128<3><<<dim3(2, MP / 128), 256, 0, stream>>>(A5, wout_t, bout, nullptr, A1,
                                                    A4, BLTOK, 256, 256, 256);
  ln256<0><<<BLTOK / 4, 256, 0, stream>>>(A4, g1, b1, A2, nullptr, BLTOK);
  // G4: h = relu(x @ Wff1 + bff1) — store pad rows too (A2 pads are zero)
  gemm128<2><<<dim3(8, MP / 128), 256, 0, stream>>>(A2, wff1_t, bff1, nullptr, nullptr,
                                                    A5, MP, 1024, 1024, 256);
  // G5: y = x + h @ Wff2 + bff2
  gemm128<3><<<dim3(2, MP / 128), 256, 0, stream>>>(A5, wff2_t, bff2, nullptr, A2,
                                                    A3, BLTOK, 256, 256, 1024);
  ln256<1><<<BLTOK / 4, 256, 0, stream>>>(A3, g2, b2, nullptr, out, BLTOK);
}

// Round 12
// 432.135 us; speedup vs baseline: 1.0996x; 1.0861x over previous
//
#include <hip/hip_runtime.h>

// ---------------------------------------------------------------------------
// DeformableTransformer encoder layer, MI355X (gfx950).
// R10 (3rd submit; GPUAcquisitionTimeouts — never measured):
//  - gemm_ln: fused GEMM(128x256 tile, 8 waves) + residual + LayerNorm for
//    G3 and G5 (N=256 -> block owns full rows). Kills 2 ln256 launches and
//    ~108MB of intermediate traffic. Epilogue: 4 rounds x 32 rows, f32 LDS
//    stride 258 (bank-audited ~2-way), 16-lane row reduce.
//  - deform_sample: persistent grid (2048 blocks, grid-stride) to remove
//    ramp/tail; internals unchanged from R9 (79us, VALU 50%, FETCH 136MB).
// Carried: quad-dedup + level-batch MLP + XCD affinity (R8/R9), gemm128 (R4).
// ---------------------------------------------------------------------------

#define BLTOK 52500   // B*L tokens
#define MP    52608   // BLTOK padded to multiple of 128
#define LSP   13125   // L (spatial length per batch)

using short8  = __attribute__((ext_vector_type(8))) short;
using ushort8v= __attribute__((ext_vector_type(8))) unsigned short;
using f32x4   = __attribute__((ext_vector_type(4))) float;
using fl2     = __attribute__((ext_vector_type(2))) float;

__device__ __forceinline__ ushort f2b(float f) {
  union { float f; unsigned u; } x; x.f = f;
  unsigned r = (x.u + 0x7fffu + ((x.u >> 16) & 1u)) >> 16;
  return (ushort)r;
}
__device__ __forceinline__ float b2f(ushort h) {
  union { unsigned u; float f; } x; x.u = ((unsigned)h) << 16;
  return x.f;
}
__device__ __forceinline__ float blo(uint u) {
  union { unsigned u; float f; } x; x.u = u << 16;
  return x.f;
}
__device__ __forceinline__ float bhi(uint u) {
  union { unsigned u; float f; } x; x.u = u & 0xffff0000u;
  return x.f;
}

#define GLDS16(gp, lp) __builtin_amdgcn_global_load_lds( \
    (const __attribute__((address_space(1))) void*)(gp), \
    (__attribute__((address_space(3))) void*)(lp), 16, 0, 0)

// ---------------- weight prep: transpose to N x K, convert bf16 -------------
__global__ __launch_bounds__(256) void prep_weights(
    const float* __restrict__ Wv, const float* __restrict__ Woff,
    const float* __restrict__ Wattn, const float* __restrict__ Wout,
    const float* __restrict__ Wff1, const float* __restrict__ Wff2,
    const float* __restrict__ boff, const float* __restrict__ battn,
    ushort* __restrict__ wv_t, ushort* __restrict__ wcat_t,
    ushort* __restrict__ wout_t, ushort* __restrict__ wff1_t,
    ushort* __restrict__ wff2_t, float* __restrict__ bcat)
{
  int i = blockIdx.x * 256 + threadIdx.x;
  if (i < 65536) {
    int n = i >> 8, k = i & 255;
    wv_t[i] = f2b(Wv[k * 256 + n]);
    return;
  }
  int j = i - 65536;
  if (j < 98304) {                       // 384 rows (320.. zero)
    int n = j >> 8, k = j & 255;
    float v = (n < 192) ? Woff[k * 192 + n]
            : (n < 288) ? Wattn[k * 96 + (n - 192)] : 0.f;
    wcat_t[j] = f2b(v);
    return;
  }
  j -= 98304;
  if (j < 65536) {
    int n = j >> 8, k = j & 255;
    wout_t[j] = f2b(Wout[k * 256 + n]);
    return;
  }
  j -= 65536;
  if (j < 262144) {
    int n = j >> 8, k = j & 255;
    wff1_t[j] = f2b(Wff1[k * 1024 + n]);
    return;
  }
  j -= 262144;
  if (j < 262144) {
    int n = j >> 10, k = j & 1023;
    wff2_t[j] = f2b(Wff2[k * 256 + n]);
    return;
  }
  j -= 262144;
  if (j < 384) bcat[j] = (j < 192) ? boff[j] : (j < 288) ? battn[j - 192] : 0.f;
}

// ---------------- activation prep: bf16 src and q=src+pos, zero pad rows ----
__global__ __launch_bounds__(256) void prep_act(
    const float* __restrict__ src, const float* __restrict__ pos,
    ushort* __restrict__ src_bf, ushort* __restrict__ q_bf)
{
  const size_t e = ((size_t)blockIdx.x * 256 + threadIdx.x) * 4;
  if (e >= (size_t)MP * 256) return;
  ushort4 sb, qb;
  if (e < (size_t)BLTOK * 256) {
    const float4 s = *(const float4*)(src + e);
    const float4 p = *(const float4*)(pos + e);
    sb.x = f2b(s.x); sb.y = f2b(s.y); sb.z = f2b(s.z); sb.w = f2b(s.w);
    qb.x = f2b(s.x + p.x); qb.y = f2b(s.y + p.y);
    qb.z = f2b(s.z + p.z); qb.w = f2b(s.w + p.w);
  } else {
    sb.x = sb.y = sb.z = sb.w = 0;
    qb.x = qb.y = qb.z = qb.w = 0;
  }
  *(ushort4*)(src_bf + e) = sb;
  *(ushort4*)(q_bf + e) = qb;
}

// ---------------- GEMM 128x128, dbuf GLDS staging, coalesced epilogue -------
// EPI: 0 = bias; 2 = relu
template <int EPI>
__global__ __launch_bounds__(256) void gemm128(
    const ushort* __restrict__ A, const ushort* __restrict__ Bt,
    const float* __restrict__ bias, ushort* __restrict__ C,
    int Mact, int Nact, int Nstr, int K)
{
  __shared__ __align__(16) ushort sm[16384];     // 32 KB
  ushort* As = sm;                               // [2][4096]
  ushort* Bs = sm + 8192;                        // [2][4096]
  float*  epf = (float*)sm;                      // epilogue: 64 x 128 f32
  const int tid = threadIdx.x;
  const int wave = tid >> 6, lane = tid & 63;
  const int n0 = blockIdx.x * 128, m0 = blockIdx.y * 128;
  const int srow = lane >> 2, skc = (lane & 3) * 8;
  const ushort* Ag = A + (size_t)(m0 + wave * 32 + srow) * K + skc;
  const ushort* Bg = Bt + (size_t)(n0 + wave * 32 + srow) * K + skc;
  const int quad = lane >> 4, l16 = lane & 15;
  const int wm = (wave & 1) * 64, wn = (wave >> 1) * 64;
  f32x4 acc[4][4] = {};

#define STAGE(buf, kk) { \
    ushort* la = As + (buf) * 4096 + wave * 1024; \
    ushort* lb = Bs + (buf) * 4096 + wave * 1024; \
    GLDS16(Ag + (kk), la); \
    GLDS16(Ag + (kk) + 16 * K, la + 512); \
    GLDS16(Bg + (kk), lb); \
    GLDS16(Bg + (kk) + 16 * K, lb + 512); }

  STAGE(0, 0);
  int cur = 0;
  for (int k0 = 0; k0 < K; k0 += 32) {
    __syncthreads();
    if (k0 + 32 < K) STAGE(cur ^ 1, k0 + 32);
    const ushort* Ab = As + cur * 4096;
    const ushort* Bb = Bs + cur * 4096;
    short8 af[4], bf[4];
#pragma unroll
    for (int i = 0; i < 4; i++)
      af[i] = *(const short8*)(&Ab[(wm + i * 16 + l16) * 32 + quad * 8]);
#pragma unroll
    for (int j = 0; j < 4; j++)
      bf[j] = *(const short8*)(&Bb[(wn + j * 16 + l16) * 32 + quad * 8]);
#pragma unroll
    for (int i = 0; i < 4; i++)
#pragma unroll
      for (int j = 0; j < 4; j++)
        acc[i][j] = __builtin_amdgcn_mfma_f32_16x16x32_bf16(af[i], bf[j],
                                                            acc[i][j], 0, 0, 0);
    cur ^= 1;
  }
#undef STAGE

  for (int half = 0; half < 2; half++) {
    __syncthreads();
    if ((wave & 1) == half) {
#pragma unroll
      for (int i = 0; i < 4; i++)
#pragma unroll
        for (int j = 0; j < 4; j++)
#pragma unroll
          for (int r = 0; r < 4; r++)
            epf[(i * 16 + quad * 4 + r) * 128 + wn + j * 16 + l16] = acc[i][j][r];
    }
    __syncthreads();
    const int gm0 = m0 + half * 64;
#pragma unroll
    for (int g = 0; g < 4; g++) {
      const int lrow = g * 16 + (tid >> 4);
      const int col0 = (tid & 15) * 8;
      const int grow = gm0 + lrow;
      const int gcol = n0 + col0;
      if (grow < Mact && gcol < Nact) {
        float v[8];
#pragma unroll
        for (int c = 0; c < 8; c++) v[c] = epf[lrow * 128 + col0 + c] + bias[gcol + c];
        if (EPI == 2) {
#pragma unroll
          for (int c = 0; c < 8; c++) v[c] = fmaxf(v[c], 0.f);
        }
        ushort8v o;
#pragma unroll
        for (int c = 0; c < 8; c++) o[c] = f2b(v[c]);
        *(ushort8v*)(C + (size_t)grow * Nstr + gcol) = o;
      }
    }
  }
}

// ---------------- fused GEMM(M x 256) + residual + LayerNorm ---------------
// 512 threads = 8 waves, tile 128(M) x 256(N); wave (wm,wn) = ((w&1)*64,
// (w>>1)*64). N=256 == full rows -> LN in epilogue. OUTF: 0 = bf16 to outb,
// 1 = f32 to outf.  y = LN( addb + A@Bt^T + bias ) * g + b
template <int OUTF>
__global__ __launch_bounds__(512) void gemm_ln(
    const ushort* __restrict__ A, const ushort* __restrict__ Bt,
    const float* __restrict__ bias, const ushort* __restrict__ addb,
    const float* __restrict__ gg, const float* __restrict__ bb,
    ushort* __restrict__ outb, float* __restrict__ outf, int K)
{
  __shared__ __align__(16) ushort sm[24576];     // 48 KB
  ushort* As = sm;                               // [2][128*32]  = 8192
  ushort* Bs = sm + 8192;                        // [2][256*32]  = 16384
  float*  epf = (float*)sm;                      // 32 rows x stride 258 f32
  const int tid = threadIdx.x;
  const int w = tid >> 6, lane = tid & 63;
  const int m0 = blockIdx.x * 128;
  const int srow = lane >> 2, skc = (lane & 3) * 8;
  const ushort* Ag = A + (size_t)(m0 + w * 16 + srow) * K + skc;
  const ushort* Bg = Bt + (size_t)(w * 32 + srow) * K + skc;
  const int quad = lane >> 4, l16 = lane & 15;
  const int wm = (w & 1) * 64, wn = (w >> 1) * 64;
  f32x4 acc[4][4] = {};

#define STAGE8(buf, kk) { \
    ushort* la = As + (buf) * 4096 + w * 512; \
    ushort* lb = Bs + (buf) * 8192 + w * 1024; \
    GLDS16(Ag + (kk), la); \
    GLDS16(Bg + (kk), lb); \
    GLDS16(Bg + (kk) + 16 * K, lb + 512); }

  STAGE8(0, 0);
  int cur = 0;
  for (int k0 = 0; k0 < K; k0 += 32) {
    __syncthreads();
    if (k0 + 32 < K) STAGE8(cur ^ 1, k0 + 32);
    const ushort* Ab = As + cur * 4096;
    const ushort* Bb = Bs + cur * 8192;
    short8 af[4], bf[4];
#pragma unroll
    for (int i = 0; i < 4; i++)
      af[i] = *(const short8*)(&Ab[(wm + i * 16 + l16) * 32 + quad * 8]);
#pragma unroll
    for (int j = 0; j < 4; j++)
      bf[j] = *(const short8*)(&Bb[(wn + j * 16 + l16) * 32 + quad * 8]);
#pragma unroll
    for (int i = 0; i < 4; i++)
#pragma unroll
      for (int j = 0; j < 4; j++)
        acc[i][j] = __builtin_amdgcn_mfma_f32_16x16x32_bf16(af[i], bf[j],
                                                            acc[i][j], 0, 0, 0);
    cur ^= 1;
  }
#undef STAGE8

  // epilogue: 4 rounds x 32 rows. epf stride 258 dwords (bank-spread, 8B ok)
  const int r2 = tid >> 4;        // 0..31 row within round
  const int cb = tid & 15;        // 16 lanes per row
#pragma unroll
  for (int q = 0; q < 4; q++) {
    __syncthreads();
    if ((w & 1) == (q >> 1)) {
#pragma unroll
      for (int i2 = 0; i2 < 2; i2++) {
        const int i = (q & 1) * 2 + i2;
        const int lr = i2 * 16 + quad * 4;   // +r
#pragma unroll
        for (int j = 0; j < 4; j++)
#pragma unroll
          for (int r = 0; r < 4; r++)
            epf[(lr + r) * 258 + wn + j * 16 + l16] = acc[i][j][r];
      }
    }
    __syncthreads();
    const int grow = m0 + q * 32 + r2;
    const bool live = (grow < BLTOK);
    float v[16];
#pragma unroll
    for (int ch = 0; ch < 4; ch++) {
      const int c0 = ch * 64 + cb * 4;
      const fl2 a = *(const fl2*)(&epf[r2 * 258 + c0]);
      const fl2 b = *(const fl2*)(&epf[r2 * 258 + c0 + 2]);
      v[ch * 4 + 0] = a.x; v[ch * 4 + 1] = a.y;
      v[ch * 4 + 2] = b.x; v[ch * 4 + 3] = b.y;
      if (live) {
        const float4 bi = *(const float4*)(bias + c0);
        const ushort4 ad = *(const ushort4*)(addb + (size_t)grow * 256 + c0);
        v[ch * 4 + 0] += bi.x + b2f(ad.x);
        v[ch * 4 + 1] += bi.y + b2f(ad.y);
        v[ch * 4 + 2] += bi.z + b2f(ad.z);
        v[ch * 4 + 3] += bi.w + b2f(ad.w);
      }
    }
    float s = 0.f, s2 = 0.f;
#pragma unroll
    for (int k = 0; k < 16; k++) { s += v[k]; s2 += v[k] * v[k]; }
#pragma unroll
    for (int o = 8; o > 0; o >>= 1) {
      s += __shfl_xor(s, o, 16);
      s2 += __shfl_xor(s2, o, 16);
    }
    const float mean = s * (1.f / 256.f);
    const float var = s2 * (1.f / 256.f) - mean * mean;
    const float rstd = rsqrtf(var + 1e-5f);
    if (live) {
#pragma unroll
      for (int ch = 0; ch < 4; ch++) {
        const int c0 = ch * 64 + cb * 4;
        const float4 g4 = *(const float4*)(gg + c0);
        const float4 b4 = *(const float4*)(bb + c0);
        float o0 = (v[ch * 4 + 0] - mean) * rstd * g4.x + b4.x;
        float o1 = (v[ch * 4 + 1] - mean) * rstd * g4.y + b4.y;
        float o2 = (v[ch * 4 + 2] - mean) * rstd * g4.z + b4.z;
        float o3 = (v[ch * 4 + 3] - mean) * rstd * g4.w + b4.w;
        if (OUTF) {
          float4 o; o.x = o0; o.y = o1; o.z = o2; o.w = o3;
          *(float4*)(outf + (size_t)grow * 256 + c0) = o;
        } else {
          ushort4 o;
          o.x = f2b(o0); o.y = f2b(o1); o.z = f2b(o2); o.w = f2b(o3);
          *(ushort4*)(outb + (size_t)grow * 256 + c0) = o;
        }
      }
    }
  }
}

// ---------------- MS-deform-attn bilinear sampling core ---------------------
// Persistent: 2048 blocks (8 XCD lanes x 256), grid-stride over slots.
// 32 lanes/token; quad-dedup; per-level 16-load batch + sched_barrier.
__global__ __launch_bounds__(256) void deform_sample(
    const ushort* __restrict__ value, const ushort* __restrict__ oa_all,
    const float* __restrict__ refp, ushort* __restrict__ outb)
{
  const int tid = threadIdx.x;
  const int xcd  = blockIdx.x & 7;
  const int batch = xcd >> 1, halfb = xcd & 1;
  const int tokBase = batch * LSP + halfb * 6564;
  const int tokEnd = batch * LSP + (halfb ? LSP : 6564);
  const int Wl[3] = {100, 50, 25};
  const int Stl[3] = {0, 10000, 12500};
  const int l = tid & 31;
  const int h = l >> 2;
  const int q = l & 3;

  for (int slot = blockIdx.x >> 3; slot < 821; slot += 256) {
    const int tok = tokBase + slot * 8 + (tid >> 5);
    if (tok >= tokEnd) continue;
    const ushort* oa = oa_all + (uint)tok * 320u;
    const float* rp = refp + (uint)tok * 6u;
    const uint base = (uint)batch * (LSP * 256u) + (uint)(l * 8);

    // quad-parallel softmax (lane q: logits q, q+4, q+8)
    const ushort* lgp = oa + 192 + h * 12 + q;
    float e0 = b2f(lgp[0]), e1 = b2f(lgp[4]), e2 = b2f(lgp[8]);
    float m3 = fmaxf(fmaxf(e0, e1), e2);
    m3 = fmaxf(m3, __shfl_xor(m3, 1, 4));
    m3 = fmaxf(m3, __shfl_xor(m3, 2, 4));
    e0 = __expf(e0 - m3); e1 = __expf(e1 - m3); e2 = __expf(e2 - m3);
    float s3 = e0 + e1 + e2;
    s3 += __shfl_xor(s3, 1, 4);
    s3 += __shfl_xor(s3, 2, 4);
    const float inv = __builtin_amdgcn_rcpf(s3);
    const float awn[3] = {e0 * inv, e1 * inv, e2 * inv};

    float ow[3][4];
    uint  orr[3][4];
#pragma unroll
    for (int lid = 0; lid < 3; lid++) {
      const int W = Wl[lid], st = Stl[lid];
      const float Wf = (float)W;
      const uint o = *(const uint*)(oa + h * 24 + lid * 8 + q * 2);
      const float aw = awn[lid];
      const float x = rp[lid * 2] * Wf - 0.5f + blo(o);
      const float y = rp[lid * 2 + 1] * Wf - 0.5f + bhi(o);
      const float x0f = floorf(x), y0f = floorf(y);
      const float wx1 = x - x0f, wy1 = y - y0f;
      const float wx0 = 1.f - wx1, wy0 = 1.f - wy1;
      const int ix0 = (int)x0f, iy0 = (int)y0f;
      const bool x0v = (ix0 >= 0) & (ix0 < W);
      const bool x1v = (ix0 + 1 >= 0) & (ix0 + 1 < W);
      const bool y0v = (iy0 >= 0) & (iy0 < W);
      const bool y1v = (iy0 + 1 >= 0) & (iy0 + 1 < W);
      const float ay0 = aw * wy0, ay1 = aw * wy1;
      ow[lid][0] = (x0v & y0v) ? ay0 * wx0 : 0.f;
      ow[lid][1] = (x1v & y0v) ? ay0 * wx1 : 0.f;
      ow[lid][2] = (x0v & y1v) ? ay1 * wx0 : 0.f;
      ow[lid][3] = (x1v & y1v) ? ay1 * wx1 : 0.f;
      const int ix0c = min(max(ix0, 0), W - 1);
      const int ix1c = min(max(ix0 + 1, 0), W - 1);
      const int iy0c = min(max(iy0, 0), W - 1);
      const int iy1c = min(max(iy0 + 1, 0), W - 1);
      orr[lid][0] = (uint)(st + iy0c * W + ix0c) * 256u;
      orr[lid][1] = (uint)(st + iy0c * W + ix1c) * 256u;
      orr[lid][2] = (uint)(st + iy1c * W + ix0c) * 256u;
      orr[lid][3] = (uint)(st + iy1c * W + ix1c) * 256u;
    }

    fl2 acc2[4] = {};
#pragma unroll
    for (int lid = 0; lid < 3; lid++) {
      float bw[4][4];
      uint4 cq[4][4];
#pragma unroll
      for (int pt = 0; pt < 4; pt++) {
#pragma unroll
        for (int c = 0; c < 4; c++) {
          bw[pt][c] = __shfl(ow[lid][c], pt, 4);
          const uint r = (uint)__shfl((int)orr[lid][c], pt, 4);
          cq[pt][c] = *(const uint4*)(value + base + r);
        }
      }
      __builtin_amdgcn_sched_barrier(0);
#pragma unroll
      for (int pt = 0; pt < 4; pt++) {
#pragma unroll
        for (int c = 0; c < 4; c++) {
          const fl2 wv = {bw[pt][c], bw[pt][c]};
          const uint* u = (const uint*)&cq[pt][c];
#pragma unroll
          for (int pp = 0; pp < 4; pp++) {
            const fl2 vv = {blo(u[pp]), bhi(u[pp])};
            acc2[pp] += wv * vv;
          }
        }
      }
    }

    ushort4 o0, o1;
    o0.x = f2b(acc2[0].x); o0.y = f2b(acc2[0].y);
    o0.z = f2b(acc2[1].x); o0.w = f2b(acc2[1].y);
    o1.x = f2b(acc2[2].x); o1.y = f2b(acc2[2].y);
    o1.z = f2b(acc2[3].x); o1.w = f2b(acc2[3].y);
    ushort* op = outb + (uint)tok * 256u + (uint)(l * 8);
    *(ushort4*)op = o0;
    *(ushort4*)(op + 4) = o1;
  }
}

// ---------------------------------------------------------------------------
extern "C" void kernel_launch(void* const* d_in, const int* in_sizes, int n_in,
                              void* d_out, int out_size, void* d_ws, size_t ws_size,
                              hipStream_t stream)
{
  const float* src   = (const float*)d_in[0];
  const float* pos   = (const float*)d_in[1];
  const float* refp  = (const float*)d_in[2];
  const float* Wv    = (const float*)d_in[3];
  const float* bv    = (const float*)d_in[4];
  const float* Woff  = (const float*)d_in[5];
  const float* boff  = (const float*)d_in[6];
  const float* Wattn = (const float*)d_in[7];
  const float* battn = (const float*)d_in[8];
  const float* Wout  = (const float*)d_in[9];
  const float* bout  = (const float*)d_in[10];
  const float* g1    = (const float*)d_in[11];
  const float* b1    = (const float*)d_in[12];
  const float* Wff1  = (const float*)d_in[13];
  const float* bff1  = (const float*)d_in[14];
  const float* Wff2  = (const float*)d_in[15];
  const float* bff2  = (const float*)d_in[16];
  const float* g2    = (const float*)d_in[17];
  const float* b2    = (const float*)d_in[18];
  float* out = (float*)d_out;
  char* ws = (char*)d_ws;

  ushort* wcat_t = (ushort*)(ws + 0);            //   196608 (384 x 256)
  ushort* wff1_t = (ushort*)(ws + 196608);       //   524288
  ushort* wff2_t = (ushort*)(ws + 720896);       //   524288
  float*  bcat   = (float*)(ws + 1245184);       //     1536
  ushort* A1 = (ushort*)(ws + 1246720);          // src_bf (lives to G3)
  ushort* A2 = (ushort*)(ws + 28182016);         // q_bf -> x_bf
  ushort* A3 = (ushort*)(ws + 55117312);         // value
  ushort* A4 = (ushort*)(ws + 81997312);         // offattn(320)
  ushort* A5 = (ushort*)(ws + 115597312);        // attn_out (head) -> h (MPx1024)
  ushort* wout_t = (ushort*)(ws + 223076352);    //   131072 (A5 tail)
  ushort* wv_t   = (ushort*)(ws + 223207424);    //   131072 (A5 tail)

  prep_weights<<<2946, 256, 0, stream>>>(Wv, Woff, Wattn, Wout, Wff1, Wff2,
                                         boff, battn,
                                         wv_t, wcat_t, wout_t, wff1_t, wff2_t, bcat);
  prep_act<<<MP / 4, 256, 0, stream>>>(src, pos, A1, A2);
  // G1: value = src @ Wv + bv
  gemm128<0><<<dim3(2, MP / 128), 256, 0, stream>>>(A1, wv_t, bv, A3,
                                                    BLTOK, 256, 256, 256);
  // G2: offattn = q @ Wcat + bcat  (N=320, tiles to 384)
  gemm128<0><<<dim3(3, MP / 128), 256, 0, stream>>>(A2, wcat_t, bcat, A4,
                                                    BLTOK, 320, 320, 256);
  // attn_out -> A5 head (persistent grid)
  deform_sample<<<2048, 256, 0, stream>>>(A3, A4, refp, A5);
  // G3+LN1 fused: x = LN(src + attn_out @ Wout + bout) -> A2 (bf16)
  gemm_ln<0><<<MP / 128, 512, 0, stream>>>(A5, wout_t, bout, A1, g1, b1,
                                           A2, nullptr, 256);
  // G4: h = relu(x @ Wff1 + bff1) — store pad rows too (A2 pads are zero)
  gemm128<2><<<dim3(8, MP / 128), 256, 0, stream>>>(A2, wff1_t, bff1, A5,
                                                    MP, 1024, 1024, 256);
  // G5+LN2 fused: out = LN(x + h @ Wff2 + bff2) -> out (f32)
  gemm_ln<1><<<MP / 128, 512, 0, stream>>>(A5, wff2_t, bff2, A2, g2, b2,
                                           nullptr, out, 1024);
}